// Round 9
// baseline (886.929 us; speedup 1.0000x reference)
//
#include <hip/hip_runtime.h>
#include <cstddef>

#define BATCH 32
#define NPTS  1024
#define K_NN  12
#define HID   64
#define BN_EPS 1e-5f

typedef short bf16x8 __attribute__((ext_vector_type(8)));
typedef float f32x4 __attribute__((ext_vector_type(4)));

// ---------------------------------------------------------------------------
// d2[j] = ||x_j||^2 (layer-0 input only; later layers fused into egapply).
// ---------------------------------------------------------------------------
template<int C>
__global__ __launch_bounds__(256) void d2_kernel(const float* __restrict__ x,
                                                 float* __restrict__ d2) {
  int gid = blockIdx.x * 256 + threadIdx.x;          // < B*N
  const float* xp = x + (size_t)gid * C;
  float s = 0.f;
#pragma unroll
  for (int c = 0; c < C; ++c) { float v = xp[c]; s = fmaf(v, v, s); }
  d2[gid] = s;
}

// ---------------------------------------------------------------------------
// Branchless exact top-12 machinery on packed u64 keys.
// key = (ordered_int(dval) << 32) | j  -> single v_cmp_lt_u64 is exact
// lexicographic (d asc, j asc) = reference top_k tie-breaking.
// ---------------------------------------------------------------------------
__device__ __forceinline__ unsigned long long dkey(float dval, int j) {
  int di = __float_as_int(dval);
  unsigned m = (unsigned)(di >> 31) | 0x80000000u;   // flip for total order
  unsigned u = (unsigned)di ^ m;
  return ((unsigned long long)u << 32) | (unsigned)j;
}

__device__ __forceinline__ void cas_u64(unsigned long long &a, unsigned long long &b) {
  unsigned long long x = a, y = b;
  bool c = y < x;
  a = c ? y : x;
  b = c ? x : y;
}

// Batcher odd-even mergesort network, n=16, 63 comparators (dense, no branches).
__device__ __forceinline__ void sort16_u64(unsigned long long (&k)[16]) {
  cas_u64(k[0],k[1]);  cas_u64(k[2],k[3]);  cas_u64(k[4],k[5]);  cas_u64(k[6],k[7]);
  cas_u64(k[8],k[9]);  cas_u64(k[10],k[11]); cas_u64(k[12],k[13]); cas_u64(k[14],k[15]);
  cas_u64(k[0],k[2]);  cas_u64(k[1],k[3]);  cas_u64(k[4],k[6]);  cas_u64(k[5],k[7]);
  cas_u64(k[8],k[10]); cas_u64(k[9],k[11]); cas_u64(k[12],k[14]); cas_u64(k[13],k[15]);
  cas_u64(k[1],k[2]);  cas_u64(k[5],k[6]);  cas_u64(k[9],k[10]); cas_u64(k[13],k[14]);
  cas_u64(k[0],k[4]);  cas_u64(k[1],k[5]);  cas_u64(k[2],k[6]);  cas_u64(k[3],k[7]);
  cas_u64(k[8],k[12]); cas_u64(k[9],k[13]); cas_u64(k[10],k[14]); cas_u64(k[11],k[15]);
  cas_u64(k[2],k[4]);  cas_u64(k[3],k[5]);  cas_u64(k[10],k[12]); cas_u64(k[11],k[13]);
  cas_u64(k[1],k[2]);  cas_u64(k[3],k[4]);  cas_u64(k[5],k[6]);
  cas_u64(k[9],k[10]); cas_u64(k[11],k[12]); cas_u64(k[13],k[14]);
  cas_u64(k[0],k[8]);  cas_u64(k[1],k[9]);  cas_u64(k[2],k[10]); cas_u64(k[3],k[11]);
  cas_u64(k[4],k[12]); cas_u64(k[5],k[13]); cas_u64(k[6],k[14]); cas_u64(k[7],k[15]);
  cas_u64(k[4],k[8]);  cas_u64(k[5],k[9]);  cas_u64(k[6],k[10]); cas_u64(k[7],k[11]);
  cas_u64(k[2],k[4]);  cas_u64(k[3],k[5]);  cas_u64(k[6],k[8]);  cas_u64(k[7],k[9]);
  cas_u64(k[10],k[12]); cas_u64(k[11],k[13]);
  cas_u64(k[1],k[2]);  cas_u64(k[3],k[4]);  cas_u64(k[5],k[6]);  cas_u64(k[7],k[8]);
  cas_u64(k[9],k[10]); cas_u64(k[11],k[12]); cas_u64(k[13],k[14]);
}

// Merge sorted-asc L[12] with sorted-asc S[0..11]; keep smallest 12 sorted.
// Half-cleaner -> asc-then-desc bitonic -> 20-CAS bitonic-12 sorter.
__device__ __forceinline__ void merge12_u64(unsigned long long (&L)[12],
                                            const unsigned long long* S) {
#pragma unroll
  for (int i = 0; i < 12; ++i) {
    unsigned long long s = S[11 - i];
    L[i] = L[i] < s ? L[i] : s;
  }
  cas_u64(L[0],L[8]);  cas_u64(L[1],L[9]);  cas_u64(L[2],L[10]); cas_u64(L[3],L[11]);
  cas_u64(L[4],L[8]);  cas_u64(L[5],L[9]);  cas_u64(L[6],L[10]); cas_u64(L[7],L[11]);
  cas_u64(L[0],L[2]);  cas_u64(L[1],L[3]);  cas_u64(L[4],L[6]);  cas_u64(L[5],L[7]);
  cas_u64(L[8],L[10]); cas_u64(L[9],L[11]);
  cas_u64(L[0],L[1]);  cas_u64(L[2],L[3]);  cas_u64(L[4],L[5]);  cas_u64(L[6],L[7]);
  cas_u64(L[8],L[9]);  cas_u64(L[10],L[11]);
}

// ---------------------------------------------------------------------------
// last-block BN finalize: after partial write + fence + atomic count, the
// 512th block of the grid reduces all 512 partial groups and writes stats.
// Device-scope fence/atomic is the documented cross-XCD mechanism; stream
// order makes stats visible to the subsequent egapply kernel.
// ---------------------------------------------------------------------------
__device__ __forceinline__ void finalize_stats(const float* __restrict__ partial,
                                               const float* __restrict__ g,
                                               const float* __restrict__ be,
                                               float* __restrict__ stats,
                                               float* sm /* [4*128] LDS */) {
  const int t   = threadIdx.x & 127;
  const int grp = threadIdx.x >> 7;                  // 0..3
  float a0 = 0.f, a1 = 0.f, a2 = 0.f, a3 = 0.f;
  const int gb0 = grp * 128;
  for (int gb = gb0; gb < gb0 + 128; gb += 4) {
    a0 += partial[(size_t)(gb + 0) * 128 + t];
    a1 += partial[(size_t)(gb + 1) * 128 + t];
    a2 += partial[(size_t)(gb + 2) * 128 + t];
    a3 += partial[(size_t)(gb + 3) * 128 + t];
  }
  sm[grp * 128 + t] = (a0 + a1) + (a2 + a3);
  __syncthreads();
  if (threadIdx.x < 128)
    sm[t] = (sm[t] + sm[128 + t]) + (sm[256 + t] + sm[384 + t]);
  __syncthreads();
  if (threadIdx.x < HID) {
    const float inv_n = 1.f / (float)(BATCH * NPTS * K_NN);
    float m = sm[t] * inv_n;
    float v = sm[HID + t] * inv_n - m * m;
    float A = g[t] * rsqrtf(v + BN_EPS);
    stats[128 + t] = A;
    stats[192 + t] = be[t] - m * A;
  }
}

// ---------------------------------------------------------------------------
// kNN C=64 via MFMA + fused egstats tail + last-block BN finalize.
// Main loop = R7 body verbatim (LDS A-tile; 69 us, 56 VGPR — R8's
// interleaved schedule blew VGPR to 128 and regressed; reverted).
// ---------------------------------------------------------------------------
__global__ __launch_bounds__(512, 2) void knn64_mfma_kernel(
    const unsigned short* __restrict__ xh, const unsigned short* __restrict__ xm,
    const unsigned short* __restrict__ xl, const float* __restrict__ d2,
    int* __restrict__ idx,
    const float* __restrict__ hxi, const float* __restrict__ hxj,
    float* __restrict__ partial, int* __restrict__ cnt,
    const float* __restrict__ g, const float* __restrict__ be,
    float* __restrict__ stats) {
  const int b    = blockIdx.y;
  const int lane = threadIdx.x & 63;
  const int wv_u = __builtin_amdgcn_readfirstlane(threadIdx.x >> 6);  // 0..7
  const int i0   = blockIdx.x * 64;
  const size_t bbase = (size_t)b * NPTS;
  const float* d2b = d2 + bbase;

  constexpr int NE = 8 * K_NN;                       // 96
  __shared__ __align__(16) char smem[60416];
  __shared__ int isLast;
  unsigned short* alds = (unsigned short*)smem;              // 25600 B
  float* slab = (float*)(smem + 25600 + wv_u * 4352);        // 8 x 4352 B
  unsigned long long* lk = (unsigned long long*)smem;        // overlay after barrier
  int* jlds = (int*)(smem + 49664);                          // 3072 B (disjoint)
  float* red1 = (float*)smem;                                // stats reduce (lk dead)
  float* red2 = (float*)(smem + 2048);

  const int qr = lane >> 4;                          // quad 0..3
  const int lr = lane & 15;

  // cooperative A-tile stage: 64 rows x {h,m,l} x 64 halves -> [row*200 + pl*64 + k]
  for (int it = threadIdx.x; it < 1536; it += 512) {
    const int row = it / 24, rem = it % 24, pl = rem >> 3, seg = rem & 7;
    const unsigned short* src = (pl == 0) ? xh : ((pl == 1) ? xm : xl);
    *(bf16x8*)(alds + row * 200 + pl * 64 + seg * 8) =
        *(const bf16x8*)(src + (bbase + i0 + row) * HID + seg * 8);
  }
  __syncthreads();

  unsigned long long L[K_NN];
#pragma unroll
  for (int k = 0; k < K_NN; ++k) L[k] = ~0ULL;

  const int j0 = wv_u * 128;

  // prefetch chunk 0's B frags
  bf16x8 Bh0, Bh1, Bm0, Bm1, Bl0, Bl1;
  {
    const size_t brow = (bbase + j0 + lr) * HID;
    Bh0 = *(const bf16x8*)(xh + brow + 0  + qr * 8);
    Bh1 = *(const bf16x8*)(xh + brow + 32 + qr * 8);
    Bm0 = *(const bf16x8*)(xm + brow + 0  + qr * 8);
    Bm1 = *(const bf16x8*)(xm + brow + 32 + qr * 8);
    Bl0 = *(const bf16x8*)(xl + brow + 0  + qr * 8);
    Bl1 = *(const bf16x8*)(xl + brow + 32 + qr * 8);
  }

#pragma unroll 1
  for (int chunk = 0; chunk < 8; ++chunk) {
    const int jb = j0 + chunk * 16;
    const bf16x8 bh0 = Bh0, bh1 = Bh1, bm0 = Bm0, bm1 = Bm1, bl0 = Bl0, bl1 = Bl1;

    f32x4 acc[4];
#pragma unroll
    for (int isub = 0; isub < 4; ++isub) acc[isub] = f32x4{0.f, 0.f, 0.f, 0.f};

#pragma unroll
    for (int isub = 0; isub < 4; ++isub) {
      const int ar = (isub * 16 + lr) * 200;         // halves
      bf16x8 Ah0 = *(const bf16x8*)(alds + ar + 0   + qr * 8);
      bf16x8 Ah1 = *(const bf16x8*)(alds + ar + 32  + qr * 8);
      bf16x8 Am0 = *(const bf16x8*)(alds + ar + 64  + qr * 8);
      bf16x8 Am1 = *(const bf16x8*)(alds + ar + 96  + qr * 8);
      bf16x8 Al0 = *(const bf16x8*)(alds + ar + 128 + qr * 8);
      bf16x8 Al1 = *(const bf16x8*)(alds + ar + 160 + qr * 8);
      f32x4 a = acc[isub];
      a = __builtin_amdgcn_mfma_f32_16x16x32_bf16(Ah0, bh0, a, 0, 0, 0);
      a = __builtin_amdgcn_mfma_f32_16x16x32_bf16(Ah1, bh1, a, 0, 0, 0);
      a = __builtin_amdgcn_mfma_f32_16x16x32_bf16(Ah0, bm0, a, 0, 0, 0);
      a = __builtin_amdgcn_mfma_f32_16x16x32_bf16(Ah1, bm1, a, 0, 0, 0);
      a = __builtin_amdgcn_mfma_f32_16x16x32_bf16(Am0, bh0, a, 0, 0, 0);
      a = __builtin_amdgcn_mfma_f32_16x16x32_bf16(Am1, bh1, a, 0, 0, 0);
      a = __builtin_amdgcn_mfma_f32_16x16x32_bf16(Ah0, bl0, a, 0, 0, 0);
      a = __builtin_amdgcn_mfma_f32_16x16x32_bf16(Ah1, bl1, a, 0, 0, 0);
      a = __builtin_amdgcn_mfma_f32_16x16x32_bf16(Al0, bh0, a, 0, 0, 0);
      a = __builtin_amdgcn_mfma_f32_16x16x32_bf16(Al1, bh1, a, 0, 0, 0);
      a = __builtin_amdgcn_mfma_f32_16x16x32_bf16(Am0, bm0, a, 0, 0, 0);
      a = __builtin_amdgcn_mfma_f32_16x16x32_bf16(Am1, bm1, a, 0, 0, 0);
      acc[isub] = a;
    }

    if (chunk < 7) {                                 // prefetch next chunk's B
      const size_t nrow = (bbase + jb + 16 + lr) * HID;
      Bh0 = *(const bf16x8*)(xh + nrow + 0  + qr * 8);
      Bh1 = *(const bf16x8*)(xh + nrow + 32 + qr * 8);
      Bm0 = *(const bf16x8*)(xm + nrow + 0  + qr * 8);
      Bm1 = *(const bf16x8*)(xm + nrow + 32 + qr * 8);
      Bl0 = *(const bf16x8*)(xl + nrow + 0  + qr * 8);
      Bl1 = *(const bf16x8*)(xl + nrow + 32 + qr * 8);
    }

    // D -> slab: row = isub*16 + qr*4 + r, col = lr (stride 17)
#pragma unroll
    for (int isub = 0; isub < 4; ++isub)
#pragma unroll
      for (int r = 0; r < 4; ++r)
        slab[(isub * 16 + qr * 4 + r) * 17 + lr] = acc[isub][r];

    // lane = i-row: build 16 keys, sort-16 network, merge into running top-12.
    unsigned long long S[16];
#pragma unroll
    for (int jj = 0; jj < 16; ++jj) {
      const int j = jb + jj;                         // uniform
      const float dot = slab[lane * 17 + jj];
      const float dval = fmaf(-2.f, dot, d2b[j]);    // d2_i dropped (row-const)
      S[jj] = dkey(dval, j);
    }
    sort16_u64(S);
    merge12_u64(L, S);
  }

  __syncthreads();                                   // A+slabs dead -> merge keys
#pragma unroll
  for (int k = 0; k < K_NN; ++k)
    lk[lane * (NE + 1) + wv_u * K_NN + k] = L[k];
  __syncthreads();

  // parallel tail merge: wave0 folds slices 1-3, wave1 folds 5-7 into 4.
  unsigned long long Lm[K_NN];
  if (wv_u < 2) {
    if (wv_u == 0) {
#pragma unroll
      for (int k = 0; k < K_NN; ++k) Lm[k] = L[k];
    } else {
#pragma unroll
      for (int k = 0; k < K_NN; ++k) Lm[k] = lk[lane * (NE + 1) + 4 * K_NN + k];
    }
#pragma unroll 1
    for (int w = 1; w < 4; ++w) {
      unsigned long long M[K_NN];
#pragma unroll
      for (int k = 0; k < K_NN; ++k)
        M[k] = lk[lane * (NE + 1) + (wv_u * 4 + w) * K_NN + k];
      merge12_u64(Lm, M);
    }
  }
  __syncthreads();
  if (wv_u == 1) {
#pragma unroll
    for (int k = 0; k < K_NN; ++k) lk[lane * (NE + 1) + 4 * K_NN + k] = Lm[k];
  }
  __syncthreads();
  if (wv_u == 0) {
    unsigned long long M[K_NN];
#pragma unroll
    for (int k = 0; k < K_NN; ++k) M[k] = lk[lane * (NE + 1) + 4 * K_NN + k];
    merge12_u64(Lm, M);
    int* op = idx + ((size_t)b * NPTS + i0 + lane) * K_NN;
#pragma unroll
    for (int k = 0; k < K_NN; ++k) {
      int jv = (int)(unsigned)(Lm[k] & 0xFFFFFFFFu);
      op[k] = jv;
      jlds[lane * K_NN + k] = jv;
    }
  }
  __syncthreads();

  // ---- fused egstats: wave w handles nodes w*8..w*8+7, lane = feature ----
  {
    const float* hxib = hxi + (bbase + i0) * HID;
    const float* hxjb = hxj + bbase * HID;
    float s1 = 0.f, s2 = 0.f;
#pragma unroll 1
    for (int t = 0; t < 8; ++t) {
      const int nl = wv_u * 8 + t;
      const float hv = hxib[(size_t)nl * HID + lane];
      int jj[K_NN];
#pragma unroll
      for (int k = 0; k < K_NN; ++k) jj[k] = jlds[nl * K_NN + k];
      float v[K_NN];
#pragma unroll
      for (int k = 0; k < K_NN; ++k) v[k] = hxjb[(size_t)jj[k] * HID + lane];
#pragma unroll
      for (int k = 0; k < K_NN; ++k) {
        float h = hv + v[k];
        s1 += h;
        s2 = fmaf(h, h, s2);
      }
    }
    red1[wv_u * HID + lane] = s1;
    red2[wv_u * HID + lane] = s2;
  }
  __syncthreads();
  if (threadIdx.x < 128) {
    const int f = threadIdx.x & 63;
    const float* r = (threadIdx.x < 64) ? red1 : red2;
    float a = 0.f;
#pragma unroll
    for (int w = 0; w < 8; ++w) a += r[w * HID + f];
    partial[((size_t)b * 16 + blockIdx.x) * 128 + threadIdx.x] = a;
  }

  // ---- last-block BN finalize (replaces the 1-block finalize kernel) ----
  __threadfence();
  if (threadIdx.x == 0) isLast = (atomicAdd(cnt, 1) == 511);
  __syncthreads();
  if (isLast) {
    __threadfence();
    finalize_stats(partial, g, be, stats, (float*)smem);
  }
}

// ---------------------------------------------------------------------------
// kNN C=3 (layer 0) + fused egstats tail + last-block BN finalize.
// ---------------------------------------------------------------------------
__global__ __launch_bounds__(512, 2) void knn3_kernel(
    const float* __restrict__ x, const float* __restrict__ d2,
    int* __restrict__ idx,
    const float* __restrict__ hxi, const float* __restrict__ hxj,
    float* __restrict__ partial, int* __restrict__ cnt,
    const float* __restrict__ g, const float* __restrict__ be,
    float* __restrict__ stats) {
  const int b    = blockIdx.y;
  const int lane = threadIdx.x & 63;
  const int wv_u = __builtin_amdgcn_readfirstlane(threadIdx.x >> 6);  // 0..7
  const int i0   = blockIdx.x * 64;
  const int i    = i0 + lane;
  const size_t bbase = (size_t)b * NPTS;
  const float* xb  = x  + bbase * 3;
  const float* d2b = d2 + bbase;

  constexpr int NE = 8 * K_NN;
  __shared__ __align__(16) char smem[53248];
  __shared__ int isLast;
  unsigned long long* lk = (unsigned long long*)smem;   // 49648 B
  int* jlds = (int*)(smem + 49664);                     // 3072 B
  float* red1 = (float*)smem;                           // overlay (lk dead)
  float* red2 = (float*)(smem + 2048);

  float xi0 = xb[(size_t)i * 3 + 0];
  float xi1 = xb[(size_t)i * 3 + 1];
  float xi2v = xb[(size_t)i * 3 + 2];

  unsigned long long L[K_NN];
#pragma unroll
  for (int k = 0; k < K_NN; ++k) L[k] = ~0ULL;

  const int j0 = wv_u * 128;
#pragma unroll 1
  for (int ch = 0; ch < 8; ++ch) {
    unsigned long long S[16];
#pragma unroll
    for (int jj = 0; jj < 16; ++jj) {
      const int j = j0 + ch * 16 + jj;               // uniform
      const float* xj = xb + (size_t)j * 3;          // uniform -> s_load
      const float d2j = d2b[j];
      float dot = fmaf(xi0, xj[0], 0.f);
      dot = fmaf(xi1, xj[1], dot);
      dot = fmaf(xi2v, xj[2], dot);
      S[jj] = dkey(fmaf(-2.f, dot, d2j), j);
    }
    sort16_u64(S);
    merge12_u64(L, S);
  }

#pragma unroll
  for (int k = 0; k < K_NN; ++k)
    lk[lane * (NE + 1) + wv_u * K_NN + k] = L[k];
  __syncthreads();

  unsigned long long Lm[K_NN];
  if (wv_u < 2) {
    if (wv_u == 0) {
#pragma unroll
      for (int k = 0; k < K_NN; ++k) Lm[k] = L[k];
    } else {
#pragma unroll
      for (int k = 0; k < K_NN; ++k) Lm[k] = lk[lane * (NE + 1) + 4 * K_NN + k];
    }
#pragma unroll 1
    for (int w = 1; w < 4; ++w) {
      unsigned long long M[K_NN];
#pragma unroll
      for (int k = 0; k < K_NN; ++k)
        M[k] = lk[lane * (NE + 1) + (wv_u * 4 + w) * K_NN + k];
      merge12_u64(Lm, M);
    }
  }
  __syncthreads();
  if (wv_u == 1) {
#pragma unroll
    for (int k = 0; k < K_NN; ++k) lk[lane * (NE + 1) + 4 * K_NN + k] = Lm[k];
  }
  __syncthreads();
  if (wv_u == 0) {
    unsigned long long M[K_NN];
#pragma unroll
    for (int k = 0; k < K_NN; ++k) M[k] = lk[lane * (NE + 1) + 4 * K_NN + k];
    merge12_u64(Lm, M);
    int* op = idx + ((size_t)b * NPTS + i0 + lane) * K_NN;
#pragma unroll
    for (int k = 0; k < K_NN; ++k) {
      int jv = (int)(unsigned)(Lm[k] & 0xFFFFFFFFu);
      op[k] = jv;
      jlds[lane * K_NN + k] = jv;
    }
  }
  __syncthreads();

  // ---- fused egstats ----
  {
    const float* hxib = hxi + (bbase + i0) * HID;
    const float* hxjb2 = hxj + bbase * HID;
    float s1 = 0.f, s2 = 0.f;
#pragma unroll 1
    for (int t = 0; t < 8; ++t) {
      const int nl = wv_u * 8 + t;
      const float hv = hxib[(size_t)nl * HID + lane];
      int jj[K_NN];
#pragma unroll
      for (int k = 0; k < K_NN; ++k) jj[k] = jlds[nl * K_NN + k];
      float v[K_NN];
#pragma unroll
      for (int k = 0; k < K_NN; ++k) v[k] = hxjb2[(size_t)jj[k] * HID + lane];
#pragma unroll
      for (int k = 0; k < K_NN; ++k) {
        float h = hv + v[k];
        s1 += h;
        s2 = fmaf(h, h, s2);
      }
    }
    red1[wv_u * HID + lane] = s1;
    red2[wv_u * HID + lane] = s2;
  }
  __syncthreads();
  if (threadIdx.x < 128) {
    const int f = threadIdx.x & 63;
    const float* r = (threadIdx.x < 64) ? red1 : red2;
    float a = 0.f;
#pragma unroll
    for (int w = 0; w < 8; ++w) a += r[w * HID + f];
    partial[((size_t)b * 16 + blockIdx.x) * 128 + threadIdx.x] = a;
  }

  // ---- last-block BN finalize ----
  __threadfence();
  if (threadIdx.x == 0) isLast = (atomicAdd(cnt, 1) == 511);
  __syncthreads();
  if (isLast) {
    __threadfence();
    finalize_stats(partial, g, be, stats, (float*)smem);
  }
}

// ---------------------------------------------------------------------------
// rowgemm2: dual-output 64x64 rowgemm, W1a-W1b folded into LDS staging.
// ---------------------------------------------------------------------------
__global__ __launch_bounds__(256) void rowgemm2_kernel(
    const float* __restrict__ X, const float* __restrict__ waL,
    const float* __restrict__ biasA,
    float* __restrict__ YA, float* __restrict__ YB) {
  __shared__ float wsa[HID * HID];
  __shared__ float wsb[HID * HID];
  for (int t = threadIdx.x; t < HID * HID; t += 256) {
    float wbv = waL[4096 + t];
    wsa[t] = waL[t] - wbv;
    wsb[t] = wbv;
  }
  __syncthreads();

  const int lane = threadIdx.x & 63;
  const int wv   = threadIdx.x >> 6;
  const int fq   = lane & 15;
  const int rg   = lane >> 4;
  const int r0   = blockIdx.x * 32 + wv * 8 + rg * 2;

  const float4* X4 = (const float4*)X;
  const float4* WA4 = (const float4*)wsa;
  const float4* WB4 = (const float4*)wsb;
  float aA0[4] = {0,0,0,0}, aA1[4] = {0,0,0,0};
  float aB0[4] = {0,0,0,0}, aB1[4] = {0,0,0,0};

#pragma unroll 2
  for (int cq = 0; cq < 16; ++cq) {
    float4 xa = X4[(size_t)r0 * 16 + cq];
    float4 xb_ = X4[(size_t)(r0 + 1) * 16 + cq];
    float ea[4] = {xa.x, xa.y, xa.z, xa.w};
    float eb[4] = {xb_.x, xb_.y, xb_.z, xb_.w};
#pragma unroll
    for (int d = 0; d < 4; ++d) {
      float4 wa4 = WA4[(cq * 4 + d) * 16 + fq];
      float4 wb4 = WB4[(cq * 4 + d) * 16 + fq];
      float wA[4] = {wa4.x, wa4.y, wa4.z, wa4.w};
      float wB[4] = {wb4.x, wb4.y, wb4.z, wb4.w};
#pragma unroll
      for (int k = 0; k < 4; ++k) {
        aA0[k] = fmaf(ea[d], wA[k], aA0[k]);
        aA1[k] = fmaf(eb[d], wA[k], aA1[k]);
        aB0[k] = fmaf(ea[d], wB[k], aB0[k]);
        aB1[k] = fmaf(eb[d], wB[k], aB1[k]);
      }
    }
  }
  float4 b4 = ((const float4*)biasA)[fq];
  float4 oA0{aA0[0] + b4.x, aA0[1] + b4.y, aA0[2] + b4.z, aA0[3] + b4.w};
  float4 oA1{aA1[0] + b4.x, aA1[1] + b4.y, aA1[2] + b4.z, aA1[3] + b4.w};
  float4 oB0{aB0[0], aB0[1], aB0[2], aB0[3]};
  float4 oB1{aB1[0], aB1[1], aB1[2], aB1[3]};
  ((float4*)YA)[(size_t)r0 * 16 + fq] = oA0;
  ((float4*)YA)[(size_t)(r0 + 1) * 16 + fq] = oA1;
  ((float4*)YB)[(size_t)r0 * 16 + fq] = oB0;
  ((float4*)YB)[(size_t)(r0 + 1) * 16 + fq] = oB1;
}

// ---------------------------------------------------------------------------
// dual3: layer-0 projections (C=3), subtraction folded into staging.
// ---------------------------------------------------------------------------
__global__ __launch_bounds__(256) void dual3_kernel(
    const float* __restrict__ x, const float* __restrict__ w0a,
    const float* __restrict__ b1,
    float* __restrict__ hxi, float* __restrict__ hxj) {
  __shared__ float Cs[3 * HID], Bs[3 * HID], bs[HID];
  for (int t = threadIdx.x; t < 3 * HID; t += 256) {
    float bv = w0a[192 + t];
    Cs[t] = w0a[t] - bv;
    Bs[t] = bv;
  }
  if (threadIdx.x < HID) bs[threadIdx.x] = b1[threadIdx.x];
  __syncthreads();

  const int lane = threadIdx.x & 63;
  const int wv   = __builtin_amdgcn_readfirstlane(threadIdx.x >> 6);
  const int node0 = blockIdx.x * 32;
#pragma unroll 1
  for (int it = 0; it < 8; ++it) {
    const int n = node0 + it * 4 + wv;               // uniform
    const float* xr = x + (size_t)n * 3;             // uniform -> s_load
    float x0 = xr[0], x1 = xr[1], x2 = xr[2];
    float hi = bs[lane];
    hi = fmaf(x0, Cs[0 * HID + lane], hi);
    hi = fmaf(x1, Cs[1 * HID + lane], hi);
    hi = fmaf(x2, Cs[2 * HID + lane], hi);
    float hj = x0 * Bs[0 * HID + lane];
    hj = fmaf(x1, Bs[1 * HID + lane], hj);
    hj = fmaf(x2, Bs[2 * HID + lane], hj);
    hxi[(size_t)n * HID + lane] = hi;
    hxj[(size_t)n * HID + lane] = hj;
  }
}

// ---------------------------------------------------------------------------
// egapply_gemm: BN-apply + relu + mean-over-K + W2 + b2 + fused d2 of the
// output row + fused bf16 3-way split of the output (feeds next knn).
// h-loop split into two accumulators (serial FMA dep chain halved).
// ---------------------------------------------------------------------------
__global__ __launch_bounds__(256) void egapply_gemm_kernel(
    const int* __restrict__ idx, const float* __restrict__ hxi,
    const float* __restrict__ hxj, const float* __restrict__ stats,
    const float* __restrict__ W2, const float* __restrict__ b2,
    float* __restrict__ out, float* __restrict__ d2out,
    unsigned short* __restrict__ xsh, unsigned short* __restrict__ xsm,
    unsigned short* __restrict__ xsl) {
  __shared__ float w2s[HID * HID];
  __shared__ float red[32][HID];
  for (int t = threadIdx.x; t < HID * HID; t += 256) w2s[t] = W2[t];

  const int lane = threadIdx.x & 63;
  const int wv   = __builtin_amdgcn_readfirstlane(threadIdx.x >> 6);
  const int node0 = blockIdx.x * 32;
  const float A = stats[128 + lane], Bc = stats[192 + lane];

#pragma unroll 1
  for (int it = 0; it < 4; ++it) {
    const int n0 = node0 + it * 8 + wv;              // uniform
    const int n1 = n0 + 4;
    const int bbase = (n0 >> 10) << 10;
    const int* ip0 = idx + (size_t)n0 * K_NN;        // uniform -> s_load
    const int* ip1 = idx + (size_t)n1 * K_NN;
    int j0[K_NN], j1[K_NN];
#pragma unroll
    for (int k = 0; k < K_NN; ++k) { j0[k] = ip0[k]; j1[k] = ip1[k]; }
    const float hv0 = hxi[(size_t)n0 * HID + lane];
    const float hv1 = hxi[(size_t)n1 * HID + lane];
    float v0[K_NN], v1[K_NN];
#pragma unroll
    for (int k = 0; k < K_NN; ++k) {
      v0[k] = hxj[(size_t)(bbase + j0[k]) * HID + lane];
      v1[k] = hxj[(size_t)(bbase + j1[k]) * HID + lane];
    }
    float a0 = 0.f, a1 = 0.f;
#pragma unroll
    for (int k = 0; k < K_NN; ++k) {
      a0 += fmaxf(fmaf(A, hv0 + v0[k], Bc), 0.f);
      a1 += fmaxf(fmaf(A, hv1 + v1[k], Bc), 0.f);
    }
    red[it * 8 + wv][lane] = a0;
    red[it * 8 + 4 + wv][lane] = a1;
  }
  __syncthreads();

  const float b2f = b2[lane];
  const float inv = 1.f / (float)K_NN;
#pragma unroll 2
  for (int p = 0; p < 8; ++p) {
    int rr = p * 4 + wv;                             // uniform row
    float acc0 = 0.f, acc1 = 0.f;
#pragma unroll 8
    for (int h = 0; h < HID; h += 2) {
      acc0 = fmaf(red[rr][h],     w2s[h * HID + lane],       acc0);
      acc1 = fmaf(red[rr][h + 1], w2s[(h + 1) * HID + lane], acc1);
    }
    float val = fmaf(acc0 + acc1, inv, b2f);
    const size_t o = (size_t)(node0 + rr) * HID + lane;
    out[o] = val;

    // bf16 3-way split (RNE, Sterbenz-exact residuals)
    unsigned u = __float_as_uint(val);
    unsigned short hh = (unsigned short)((u + 0x7FFFu + ((u >> 16) & 1u)) >> 16);
    float r1 = val - __uint_as_float((unsigned)hh << 16);
    unsigned ur = __float_as_uint(r1);
    unsigned short mm = (unsigned short)((ur + 0x7FFFu + ((ur >> 16) & 1u)) >> 16);
    float r2 = r1 - __uint_as_float((unsigned)mm << 16);
    unsigned ur2 = __float_as_uint(r2);
    unsigned short ll = (unsigned short)((ur2 + 0x7FFFu + ((ur2 >> 16) & 1u)) >> 16);
    xsh[o] = hh; xsm[o] = mm; xsl[o] = ll;

    float sq = val * val;                            // fused d2 of the row
#pragma unroll
    for (int off = 1; off < 64; off <<= 1) sq += __shfl_xor(sq, off, 64);
    if (lane == 0) d2out[node0 + rr] = sq;
  }
}

// ---------------------------------------------------------------------------
__global__ __launch_bounds__(256) void pool_kernel(const float* __restrict__ h,
                                                   float* __restrict__ pooled) {
  const int b = blockIdx.x;
  const int f = threadIdx.x & 63;
  const int gsz = threadIdx.x >> 6;
  __shared__ float red[4][HID];
  float s = 0.f;
  for (int n = gsz; n < NPTS; n += 4) s += h[((size_t)b * NPTS + n) * HID + f];
  red[gsz][f] = s;
  __syncthreads();
  if (threadIdx.x < HID)
    pooled[b * HID + f] = ((red[0][f] + red[1][f]) + (red[2][f] + red[3][f])) * (1.f / (float)NPTS);
}

__global__ __launch_bounds__(256) void head_kernel(const float* __restrict__ pooled,
    const float* __restrict__ wf1, const float* __restrict__ bf1,
    const float* __restrict__ gf, const float* __restrict__ bef,
    const float* __restrict__ wf2, const float* __restrict__ bf2,
    float* __restrict__ out) {
  __shared__ float pl[BATCH * HID];
  __shared__ float t[BATCH * 32];
  __shared__ float Ab[32], Bb[32];
  for (int i = threadIdx.x; i < BATCH * HID; i += 256) pl[i] = pooled[i];
  __syncthreads();
  for (int i = threadIdx.x; i < BATCH * 32; i += 256) {
    int s = i >> 5, f1 = i & 31;
    float acc = bf1[f1];
    for (int h = 0; h < HID; ++h) acc = fmaf(pl[s * HID + h], wf1[h * 32 + f1], acc);
    t[i] = acc;
  }
  __syncthreads();
  if (threadIdx.x < 32) {
    int f1 = threadIdx.x;
    float m = 0.f;
    for (int s = 0; s < BATCH; ++s) m += t[s * 32 + f1];
    m *= (1.f / (float)BATCH);
    float v = 0.f;
    for (int s = 0; s < BATCH; ++s) { float d = t[s * 32 + f1] - m; v = fmaf(d, d, v); }
    v *= (1.f / (float)BATCH);
    float A = gf[f1] * rsqrtf(v + BN_EPS);
    Ab[f1] = A; Bb[f1] = bef[f1] - m * A;
  }
  __syncthreads();
  for (int i = threadIdx.x; i < BATCH * 32; i += 256) {
    int f1 = i & 31;
    t[i] = fmaxf(fmaf(Ab[f1], t[i], Bb[f1]), 0.f);
  }
  __syncthreads();
  if (threadIdx.x < BATCH * 2) {
    int s = threadIdx.x >> 1, o = threadIdx.x & 1;
    float acc = bf2[o];
    for (int f1 = 0; f1 < 32; ++f1) acc = fmaf(t[s * 32 + f1], wf2[f1 * 2 + o], acc);
    out[s * 2 + o] = acc;
  }
}

// ---------------------------------------------------------------------------
extern "C" void kernel_launch(void* const* d_in, const int* in_sizes, int n_in,
                              void* d_out, int out_size, void* d_ws, size_t ws_size,
                              hipStream_t stream) {
  const float* x   = (const float*)d_in[0];
  const float* w0a = (const float*)d_in[1];
  const float* b0a = (const float*)d_in[2];
  const float* g0  = (const float*)d_in[3];
  const float* be0 = (const float*)d_in[4];
  const float* w0b = (const float*)d_in[5];
  const float* b0b = (const float*)d_in[6];
  const float* wa  = (const float*)d_in[7];
  const float* ba  = (const float*)d_in[8];
  const float* ga  = (const float*)d_in[9];
  const float* bea = (const float*)d_in[10];
  const float* wb  = (const float*)d_in[11];
  const float* bb  = (const float*)d_in[12];
  const float* wf1 = (const float*)d_in[13];
  const float* bf1 = (const float*)d_in[14];
  const float* gf  = (const float*)d_in[15];
  const float* bef = (const float*)d_in[16];
  const float* wf2 = (const float*)d_in[17];
  const float* bf2 = (const float*)d_in[18];

  float* ws = (float*)d_ws;
  const size_t HN = (size_t)BATCH * NPTS * HID;         // 2,097,152
  const size_t ROWS = (size_t)BATCH * NPTS;             // 32768
  float* bufA    = ws;                                  // HN
  float* bufB    = bufA + HN;                           // HN
  float* hxi     = bufB + HN;                           // HN
  float* hxjb    = hxi + HN;                            // HN
  int*   idxb    = (int*)(hxjb + HN);                   // ROWS*12
  float* d2buf   = (float*)(idxb + ROWS * K_NN);        // ROWS
  float* stats   = d2buf + ROWS;                        // 256
  float* partial = stats + 256;                         // 512*128 used
  int*   cnts    = (int*)(partial + 512 * 128);         // 4 counters
  float* pooled  = partial + 1024 * 128;                // 2048
  unsigned short* xsh = (unsigned short*)(pooled + 2048);   // HN bf16
  unsigned short* xsm = xsh + HN;
  unsigned short* xsl = xsm + HN;
  // total ~46 MB of workspace

  hipMemsetAsync(cnts, 0, 4 * sizeof(int), stream);     // zero layer counters

  // ---- layer 0 (C=3, gather path) ----
  d2_kernel<3><<<(int)(ROWS / 256), 256, 0, stream>>>(x, d2buf);
  dual3_kernel<<<1024, 256, 0, stream>>>(x, w0a, b0a, hxi, hxjb);
  knn3_kernel<<<dim3(16, BATCH), 512, 0, stream>>>(x, d2buf, idxb, hxi, hxjb,
                                                   partial, cnts + 0, g0, be0, stats);
  egapply_gemm_kernel<<<1024, 256, 0, stream>>>(idxb, hxi, hxjb, stats, w0b, b0b,
                                                bufA, d2buf, xsh, xsm, xsl);

  // ---- layers 1..3 (rowgemm2 -> fused knn64+stats+finalize -> egapply) ----
  const float* cur = bufA;
  float* nxt = bufB;
  for (int i = 0; i < 3; ++i) {
    rowgemm2_kernel<<<(int)(ROWS / 32), 256, 0, stream>>>(cur, wa + (size_t)i * 8192,
                                                          ba + i * HID, hxi, hxjb);
    knn64_mfma_kernel<<<dim3(16, BATCH), 512, 0, stream>>>(xsh, xsm, xsl, d2buf, idxb,
                                                           hxi, hxjb, partial, cnts + 1 + i,
                                                           ga + i * HID, bea + i * HID, stats);
    egapply_gemm_kernel<<<1024, 256, 0, stream>>>(idxb, hxi, hxjb, stats,
                                                  wb + (size_t)i * 4096, bb + i * HID,
                                                  nxt, d2buf, xsh, xsm, xsl);
    const float* t = cur; cur = nxt; nxt = (float*)t;
  }

  pool_kernel<<<BATCH, 256, 0, stream>>>(cur, pooled);
  head_kernel<<<1, 256, 0, stream>>>(pooled, wf1, bf1, gf, bef, wf2, bf2, (float*)d_out);
}

// Round 10
// 494.093 us; speedup vs baseline: 1.7951x; 1.7951x over previous
//
#include <hip/hip_runtime.h>
#include <cstddef>

#define BATCH 32
#define NPTS  1024
#define K_NN  12
#define HID   64
#define BN_EPS 1e-5f

typedef short bf16x8 __attribute__((ext_vector_type(8)));
typedef float f32x4 __attribute__((ext_vector_type(4)));

// ---------------------------------------------------------------------------
// Branchless exact top-12 machinery on packed u64 keys.
// key = (ordered_int(dval) << 32) | j  -> single v_cmp_lt_u64 is exact
// lexicographic (d asc, j asc) = reference top_k tie-breaking.
// ---------------------------------------------------------------------------
__device__ __forceinline__ unsigned long long dkey(float dval, int j) {
  int di = __float_as_int(dval);
  unsigned m = (unsigned)(di >> 31) | 0x80000000u;   // flip for total order
  unsigned u = (unsigned)di ^ m;
  return ((unsigned long long)u << 32) | (unsigned)j;
}

__device__ __forceinline__ void cas_u64(unsigned long long &a, unsigned long long &b) {
  unsigned long long x = a, y = b;
  bool c = y < x;
  a = c ? y : x;
  b = c ? x : y;
}

// Batcher odd-even mergesort network, n=16, 63 comparators (dense, no branches).
__device__ __forceinline__ void sort16_u64(unsigned long long (&k)[16]) {
  cas_u64(k[0],k[1]);  cas_u64(k[2],k[3]);  cas_u64(k[4],k[5]);  cas_u64(k[6],k[7]);
  cas_u64(k[8],k[9]);  cas_u64(k[10],k[11]); cas_u64(k[12],k[13]); cas_u64(k[14],k[15]);
  cas_u64(k[0],k[2]);  cas_u64(k[1],k[3]);  cas_u64(k[4],k[6]);  cas_u64(k[5],k[7]);
  cas_u64(k[8],k[10]); cas_u64(k[9],k[11]); cas_u64(k[12],k[14]); cas_u64(k[13],k[15]);
  cas_u64(k[1],k[2]);  cas_u64(k[5],k[6]);  cas_u64(k[9],k[10]); cas_u64(k[13],k[14]);
  cas_u64(k[0],k[4]);  cas_u64(k[1],k[5]);  cas_u64(k[2],k[6]);  cas_u64(k[3],k[7]);
  cas_u64(k[8],k[12]); cas_u64(k[9],k[13]); cas_u64(k[10],k[14]); cas_u64(k[11],k[15]);
  cas_u64(k[2],k[4]);  cas_u64(k[3],k[5]);  cas_u64(k[10],k[12]); cas_u64(k[11],k[13]);
  cas_u64(k[1],k[2]);  cas_u64(k[3],k[4]);  cas_u64(k[5],k[6]);
  cas_u64(k[9],k[10]); cas_u64(k[11],k[12]); cas_u64(k[13],k[14]);
  cas_u64(k[0],k[8]);  cas_u64(k[1],k[9]);  cas_u64(k[2],k[10]); cas_u64(k[3],k[11]);
  cas_u64(k[4],k[12]); cas_u64(k[5],k[13]); cas_u64(k[6],k[14]); cas_u64(k[7],k[15]);
  cas_u64(k[4],k[8]);  cas_u64(k[5],k[9]);  cas_u64(k[6],k[10]); cas_u64(k[7],k[11]);
  cas_u64(k[2],k[4]);  cas_u64(k[3],k[5]);  cas_u64(k[6],k[8]);  cas_u64(k[7],k[9]);
  cas_u64(k[10],k[12]); cas_u64(k[11],k[13]);
  cas_u64(k[1],k[2]);  cas_u64(k[3],k[4]);  cas_u64(k[5],k[6]);  cas_u64(k[7],k[8]);
  cas_u64(k[9],k[10]); cas_u64(k[11],k[12]); cas_u64(k[13],k[14]);
}

// Merge sorted-asc L[12] with sorted-asc S[0..11]; keep smallest 12 sorted.
// Half-cleaner -> asc-then-desc bitonic -> 20-CAS bitonic-12 sorter.
__device__ __forceinline__ void merge12_u64(unsigned long long (&L)[12],
                                            const unsigned long long* S) {
#pragma unroll
  for (int i = 0; i < 12; ++i) {
    unsigned long long s = S[11 - i];
    L[i] = L[i] < s ? L[i] : s;
  }
  cas_u64(L[0],L[8]);  cas_u64(L[1],L[9]);  cas_u64(L[2],L[10]); cas_u64(L[3],L[11]);
  cas_u64(L[4],L[8]);  cas_u64(L[5],L[9]);  cas_u64(L[6],L[10]); cas_u64(L[7],L[11]);
  cas_u64(L[0],L[2]);  cas_u64(L[1],L[3]);  cas_u64(L[4],L[6]);  cas_u64(L[5],L[7]);
  cas_u64(L[8],L[10]); cas_u64(L[9],L[11]);
  cas_u64(L[0],L[1]);  cas_u64(L[2],L[3]);  cas_u64(L[4],L[5]);  cas_u64(L[6],L[7]);
  cas_u64(L[8],L[9]);  cas_u64(L[10],L[11]);
}

// ---------------------------------------------------------------------------
// kNN C=64 via MFMA + fused egstats tail (R7 body verbatim — 69 us, 56
// VGPR; R8's interleave blew VGPR, R9's per-block __threadfence cost ~90 us
// in cross-XCD L2 writeback. Both reverted.)
// ---------------------------------------------------------------------------
__global__ __launch_bounds__(512, 2) void knn64_mfma_kernel(
    const unsigned short* __restrict__ xh, const unsigned short* __restrict__ xm,
    const unsigned short* __restrict__ xl, const float* __restrict__ d2,
    int* __restrict__ idx,
    const float* __restrict__ hxi, const float* __restrict__ hxj,
    float* __restrict__ partial) {
  const int b    = blockIdx.y;
  const int lane = threadIdx.x & 63;
  const int wv_u = __builtin_amdgcn_readfirstlane(threadIdx.x >> 6);  // 0..7
  const int i0   = blockIdx.x * 64;
  const size_t bbase = (size_t)b * NPTS;
  const float* d2b = d2 + bbase;

  constexpr int NE = 8 * K_NN;                       // 96
  __shared__ __align__(16) char smem[60416];
  unsigned short* alds = (unsigned short*)smem;              // 25600 B
  float* slab = (float*)(smem + 25600 + wv_u * 4352);        // 8 x 4352 B
  unsigned long long* lk = (unsigned long long*)smem;        // overlay after barrier
  int* jlds = (int*)(smem + 49664);                          // 3072 B (disjoint)
  float* red1 = (float*)smem;                                // stats reduce (lk dead)
  float* red2 = (float*)(smem + 2048);

  const int qr = lane >> 4;                          // quad 0..3
  const int lr = lane & 15;

  // cooperative A-tile stage: 64 rows x {h,m,l} x 64 halves -> [row*200 + pl*64 + k]
  for (int it = threadIdx.x; it < 1536; it += 512) {
    const int row = it / 24, rem = it % 24, pl = rem >> 3, seg = rem & 7;
    const unsigned short* src = (pl == 0) ? xh : ((pl == 1) ? xm : xl);
    *(bf16x8*)(alds + row * 200 + pl * 64 + seg * 8) =
        *(const bf16x8*)(src + (bbase + i0 + row) * HID + seg * 8);
  }
  __syncthreads();

  unsigned long long L[K_NN];
#pragma unroll
  for (int k = 0; k < K_NN; ++k) L[k] = ~0ULL;

  const int j0 = wv_u * 128;

  // prefetch chunk 0's B frags
  bf16x8 Bh0, Bh1, Bm0, Bm1, Bl0, Bl1;
  {
    const size_t brow = (bbase + j0 + lr) * HID;
    Bh0 = *(const bf16x8*)(xh + brow + 0  + qr * 8);
    Bh1 = *(const bf16x8*)(xh + brow + 32 + qr * 8);
    Bm0 = *(const bf16x8*)(xm + brow + 0  + qr * 8);
    Bm1 = *(const bf16x8*)(xm + brow + 32 + qr * 8);
    Bl0 = *(const bf16x8*)(xl + brow + 0  + qr * 8);
    Bl1 = *(const bf16x8*)(xl + brow + 32 + qr * 8);
  }

#pragma unroll 1
  for (int chunk = 0; chunk < 8; ++chunk) {
    const int jb = j0 + chunk * 16;
    const bf16x8 bh0 = Bh0, bh1 = Bh1, bm0 = Bm0, bm1 = Bm1, bl0 = Bl0, bl1 = Bl1;

    f32x4 acc[4];
#pragma unroll
    for (int isub = 0; isub < 4; ++isub) acc[isub] = f32x4{0.f, 0.f, 0.f, 0.f};

#pragma unroll
    for (int isub = 0; isub < 4; ++isub) {
      const int ar = (isub * 16 + lr) * 200;         // halves
      bf16x8 Ah0 = *(const bf16x8*)(alds + ar + 0   + qr * 8);
      bf16x8 Ah1 = *(const bf16x8*)(alds + ar + 32  + qr * 8);
      bf16x8 Am0 = *(const bf16x8*)(alds + ar + 64  + qr * 8);
      bf16x8 Am1 = *(const bf16x8*)(alds + ar + 96  + qr * 8);
      bf16x8 Al0 = *(const bf16x8*)(alds + ar + 128 + qr * 8);
      bf16x8 Al1 = *(const bf16x8*)(alds + ar + 160 + qr * 8);
      f32x4 a = acc[isub];
      a = __builtin_amdgcn_mfma_f32_16x16x32_bf16(Ah0, bh0, a, 0, 0, 0);
      a = __builtin_amdgcn_mfma_f32_16x16x32_bf16(Ah1, bh1, a, 0, 0, 0);
      a = __builtin_amdgcn_mfma_f32_16x16x32_bf16(Ah0, bm0, a, 0, 0, 0);
      a = __builtin_amdgcn_mfma_f32_16x16x32_bf16(Ah1, bm1, a, 0, 0, 0);
      a = __builtin_amdgcn_mfma_f32_16x16x32_bf16(Am0, bh0, a, 0, 0, 0);
      a = __builtin_amdgcn_mfma_f32_16x16x32_bf16(Am1, bh1, a, 0, 0, 0);
      a = __builtin_amdgcn_mfma_f32_16x16x32_bf16(Ah0, bl0, a, 0, 0, 0);
      a = __builtin_amdgcn_mfma_f32_16x16x32_bf16(Ah1, bl1, a, 0, 0, 0);
      a = __builtin_amdgcn_mfma_f32_16x16x32_bf16(Al0, bh0, a, 0, 0, 0);
      a = __builtin_amdgcn_mfma_f32_16x16x32_bf16(Al1, bh1, a, 0, 0, 0);
      a = __builtin_amdgcn_mfma_f32_16x16x32_bf16(Am0, bm0, a, 0, 0, 0);
      a = __builtin_amdgcn_mfma_f32_16x16x32_bf16(Am1, bm1, a, 0, 0, 0);
      acc[isub] = a;
    }

    if (chunk < 7) {                                 // prefetch next chunk's B
      const size_t nrow = (bbase + jb + 16 + lr) * HID;
      Bh0 = *(const bf16x8*)(xh + nrow + 0  + qr * 8);
      Bh1 = *(const bf16x8*)(xh + nrow + 32 + qr * 8);
      Bm0 = *(const bf16x8*)(xm + nrow + 0  + qr * 8);
      Bm1 = *(const bf16x8*)(xm + nrow + 32 + qr * 8);
      Bl0 = *(const bf16x8*)(xl + nrow + 0  + qr * 8);
      Bl1 = *(const bf16x8*)(xl + nrow + 32 + qr * 8);
    }

    // D -> slab: row = isub*16 + qr*4 + r, col = lr (stride 17)
#pragma unroll
    for (int isub = 0; isub < 4; ++isub)
#pragma unroll
      for (int r = 0; r < 4; ++r)
        slab[(isub * 16 + qr * 4 + r) * 17 + lr] = acc[isub][r];

    // lane = i-row: build 16 keys, sort-16 network, merge into running top-12.
    unsigned long long S[16];
#pragma unroll
    for (int jj = 0; jj < 16; ++jj) {
      const int j = jb + jj;                         // uniform
      const float dot = slab[lane * 17 + jj];
      const float dval = fmaf(-2.f, dot, d2b[j]);    // d2_i dropped (row-const)
      S[jj] = dkey(dval, j);
    }
    sort16_u64(S);
    merge12_u64(L, S);
  }

  __syncthreads();                                   // A+slabs dead -> merge keys
#pragma unroll
  for (int k = 0; k < K_NN; ++k)
    lk[lane * (NE + 1) + wv_u * K_NN + k] = L[k];
  __syncthreads();

  // parallel tail merge: wave0 folds slices 1-3, wave1 folds 5-7 into 4.
  unsigned long long Lm[K_NN];
  if (wv_u < 2) {
    if (wv_u == 0) {
#pragma unroll
      for (int k = 0; k < K_NN; ++k) Lm[k] = L[k];
    } else {
#pragma unroll
      for (int k = 0; k < K_NN; ++k) Lm[k] = lk[lane * (NE + 1) + 4 * K_NN + k];
    }
#pragma unroll 1
    for (int w = 1; w < 4; ++w) {
      unsigned long long M[K_NN];
#pragma unroll
      for (int k = 0; k < K_NN; ++k)
        M[k] = lk[lane * (NE + 1) + (wv_u * 4 + w) * K_NN + k];
      merge12_u64(Lm, M);
    }
  }
  __syncthreads();
  if (wv_u == 1) {
#pragma unroll
    for (int k = 0; k < K_NN; ++k) lk[lane * (NE + 1) + 4 * K_NN + k] = Lm[k];
  }
  __syncthreads();
  if (wv_u == 0) {
    unsigned long long M[K_NN];
#pragma unroll
    for (int k = 0; k < K_NN; ++k) M[k] = lk[lane * (NE + 1) + 4 * K_NN + k];
    merge12_u64(Lm, M);
    int* op = idx + ((size_t)b * NPTS + i0 + lane) * K_NN;
#pragma unroll
    for (int k = 0; k < K_NN; ++k) {
      int jv = (int)(unsigned)(Lm[k] & 0xFFFFFFFFu);
      op[k] = jv;
      jlds[lane * K_NN + k] = jv;
    }
  }
  __syncthreads();

  // ---- fused egstats: wave w handles nodes w*8..w*8+7, lane = feature ----
  {
    const float* hxib = hxi + (bbase + i0) * HID;
    const float* hxjb = hxj + bbase * HID;
    float s1 = 0.f, s2 = 0.f;
#pragma unroll 1
    for (int t = 0; t < 8; ++t) {
      const int nl = wv_u * 8 + t;
      const float hv = hxib[(size_t)nl * HID + lane];
      int jj[K_NN];
#pragma unroll
      for (int k = 0; k < K_NN; ++k) jj[k] = jlds[nl * K_NN + k];
      float v[K_NN];
#pragma unroll
      for (int k = 0; k < K_NN; ++k) v[k] = hxjb[(size_t)jj[k] * HID + lane];
#pragma unroll
      for (int k = 0; k < K_NN; ++k) {
        float h = hv + v[k];
        s1 += h;
        s2 = fmaf(h, h, s2);
      }
    }
    red1[wv_u * HID + lane] = s1;
    red2[wv_u * HID + lane] = s2;
  }
  __syncthreads();
  if (threadIdx.x < 128) {
    const int f = threadIdx.x & 63;
    const float* r = (threadIdx.x < 64) ? red1 : red2;
    float a = 0.f;
#pragma unroll
    for (int w = 0; w < 8; ++w) a += r[w * HID + f];
    partial[((size_t)b * 16 + blockIdx.x) * 128 + threadIdx.x] = a;
  }
}

// ---------------------------------------------------------------------------
// kNN C=3 (layer 0) + fused egstats tail (R7 body verbatim).
// ---------------------------------------------------------------------------
__global__ __launch_bounds__(512, 2) void knn3_kernel(
    const float* __restrict__ x, const float* __restrict__ d2,
    int* __restrict__ idx,
    const float* __restrict__ hxi, const float* __restrict__ hxj,
    float* __restrict__ partial) {
  const int b    = blockIdx.y;
  const int lane = threadIdx.x & 63;
  const int wv_u = __builtin_amdgcn_readfirstlane(threadIdx.x >> 6);  // 0..7
  const int i0   = blockIdx.x * 64;
  const int i    = i0 + lane;
  const size_t bbase = (size_t)b * NPTS;
  const float* xb  = x  + bbase * 3;
  const float* d2b = d2 + bbase;

  constexpr int NE = 8 * K_NN;
  __shared__ __align__(16) char smem[53248];
  unsigned long long* lk = (unsigned long long*)smem;   // 49648 B
  int* jlds = (int*)(smem + 49664);                     // 3072 B
  float* red1 = (float*)smem;                           // overlay (lk dead)
  float* red2 = (float*)(smem + 2048);

  float xi0 = xb[(size_t)i * 3 + 0];
  float xi1 = xb[(size_t)i * 3 + 1];
  float xi2v = xb[(size_t)i * 3 + 2];

  unsigned long long L[K_NN];
#pragma unroll
  for (int k = 0; k < K_NN; ++k) L[k] = ~0ULL;

  const int j0 = wv_u * 128;
#pragma unroll 1
  for (int ch = 0; ch < 8; ++ch) {
    unsigned long long S[16];
#pragma unroll
    for (int jj = 0; jj < 16; ++jj) {
      const int j = j0 + ch * 16 + jj;               // uniform
      const float* xj = xb + (size_t)j * 3;          // uniform -> s_load
      const float d2j = d2b[j];
      float dot = fmaf(xi0, xj[0], 0.f);
      dot = fmaf(xi1, xj[1], dot);
      dot = fmaf(xi2v, xj[2], dot);
      S[jj] = dkey(fmaf(-2.f, dot, d2j), j);
    }
    sort16_u64(S);
    merge12_u64(L, S);
  }

#pragma unroll
  for (int k = 0; k < K_NN; ++k)
    lk[lane * (NE + 1) + wv_u * K_NN + k] = L[k];
  __syncthreads();

  unsigned long long Lm[K_NN];
  if (wv_u < 2) {
    if (wv_u == 0) {
#pragma unroll
      for (int k = 0; k < K_NN; ++k) Lm[k] = L[k];
    } else {
#pragma unroll
      for (int k = 0; k < K_NN; ++k) Lm[k] = lk[lane * (NE + 1) + 4 * K_NN + k];
    }
#pragma unroll 1
    for (int w = 1; w < 4; ++w) {
      unsigned long long M[K_NN];
#pragma unroll
      for (int k = 0; k < K_NN; ++k)
        M[k] = lk[lane * (NE + 1) + (wv_u * 4 + w) * K_NN + k];
      merge12_u64(Lm, M);
    }
  }
  __syncthreads();
  if (wv_u == 1) {
#pragma unroll
    for (int k = 0; k < K_NN; ++k) lk[lane * (NE + 1) + 4 * K_NN + k] = Lm[k];
  }
  __syncthreads();
  if (wv_u == 0) {
    unsigned long long M[K_NN];
#pragma unroll
    for (int k = 0; k < K_NN; ++k) M[k] = lk[lane * (NE + 1) + 4 * K_NN + k];
    merge12_u64(Lm, M);
    int* op = idx + ((size_t)b * NPTS + i0 + lane) * K_NN;
#pragma unroll
    for (int k = 0; k < K_NN; ++k) {
      int jv = (int)(unsigned)(Lm[k] & 0xFFFFFFFFu);
      op[k] = jv;
      jlds[lane * K_NN + k] = jv;
    }
  }
  __syncthreads();

  // ---- fused egstats ----
  {
    const float* hxib = hxi + (bbase + i0) * HID;
    const float* hxjb2 = hxj + bbase * HID;
    float s1 = 0.f, s2 = 0.f;
#pragma unroll 1
    for (int t = 0; t < 8; ++t) {
      const int nl = wv_u * 8 + t;
      const float hv = hxib[(size_t)nl * HID + lane];
      int jj[K_NN];
#pragma unroll
      for (int k = 0; k < K_NN; ++k) jj[k] = jlds[nl * K_NN + k];
      float v[K_NN];
#pragma unroll
      for (int k = 0; k < K_NN; ++k) v[k] = hxjb2[(size_t)jj[k] * HID + lane];
#pragma unroll
      for (int k = 0; k < K_NN; ++k) {
        float h = hv + v[k];
        s1 += h;
        s2 = fmaf(h, h, s2);
      }
    }
    red1[wv_u * HID + lane] = s1;
    red2[wv_u * HID + lane] = s2;
  }
  __syncthreads();
  if (threadIdx.x < 128) {
    const int f = threadIdx.x & 63;
    const float* r = (threadIdx.x < 64) ? red1 : red2;
    float a = 0.f;
#pragma unroll
    for (int w = 0; w < 8; ++w) a += r[w * HID + f];
    partial[((size_t)b * 16 + blockIdx.x) * 128 + threadIdx.x] = a;
  }
}

// ---------------------------------------------------------------------------
// rowgemm2: dual-output 64x64 rowgemm, W1a-W1b folded into LDS staging.
// ---------------------------------------------------------------------------
__global__ __launch_bounds__(256) void rowgemm2_kernel(
    const float* __restrict__ X, const float* __restrict__ waL,
    const float* __restrict__ biasA,
    float* __restrict__ YA, float* __restrict__ YB) {
  __shared__ float wsa[HID * HID];
  __shared__ float wsb[HID * HID];
  for (int t = threadIdx.x; t < HID * HID; t += 256) {
    float wbv = waL[4096 + t];
    wsa[t] = waL[t] - wbv;
    wsb[t] = wbv;
  }
  __syncthreads();

  const int lane = threadIdx.x & 63;
  const int wv   = threadIdx.x >> 6;
  const int fq   = lane & 15;
  const int rg   = lane >> 4;
  const int r0   = blockIdx.x * 32 + wv * 8 + rg * 2;

  const float4* X4 = (const float4*)X;
  const float4* WA4 = (const float4*)wsa;
  const float4* WB4 = (const float4*)wsb;
  float aA0[4] = {0,0,0,0}, aA1[4] = {0,0,0,0};
  float aB0[4] = {0,0,0,0}, aB1[4] = {0,0,0,0};

#pragma unroll 2
  for (int cq = 0; cq < 16; ++cq) {
    float4 xa = X4[(size_t)r0 * 16 + cq];
    float4 xb_ = X4[(size_t)(r0 + 1) * 16 + cq];
    float ea[4] = {xa.x, xa.y, xa.z, xa.w};
    float eb[4] = {xb_.x, xb_.y, xb_.z, xb_.w};
#pragma unroll
    for (int d = 0; d < 4; ++d) {
      float4 wa4 = WA4[(cq * 4 + d) * 16 + fq];
      float4 wb4 = WB4[(cq * 4 + d) * 16 + fq];
      float wA[4] = {wa4.x, wa4.y, wa4.z, wa4.w};
      float wB[4] = {wb4.x, wb4.y, wb4.z, wb4.w};
#pragma unroll
      for (int k = 0; k < 4; ++k) {
        aA0[k] = fmaf(ea[d], wA[k], aA0[k]);
        aA1[k] = fmaf(eb[d], wA[k], aA1[k]);
        aB0[k] = fmaf(ea[d], wB[k], aB0[k]);
        aB1[k] = fmaf(eb[d], wB[k], aB1[k]);
      }
    }
  }
  float4 b4 = ((const float4*)biasA)[fq];
  float4 oA0{aA0[0] + b4.x, aA0[1] + b4.y, aA0[2] + b4.z, aA0[3] + b4.w};
  float4 oA1{aA1[0] + b4.x, aA1[1] + b4.y, aA1[2] + b4.z, aA1[3] + b4.w};
  float4 oB0{aB0[0], aB0[1], aB0[2], aB0[3]};
  float4 oB1{aB1[0], aB1[1], aB1[2], aB1[3]};
  ((float4*)YA)[(size_t)r0 * 16 + fq] = oA0;
  ((float4*)YA)[(size_t)(r0 + 1) * 16 + fq] = oA1;
  ((float4*)YB)[(size_t)r0 * 16 + fq] = oB0;
  ((float4*)YB)[(size_t)(r0 + 1) * 16 + fq] = oB1;
}

// ---------------------------------------------------------------------------
// dual3: layer-0 projections (C=3), subtraction folded into staging;
// d2 of the input row folded in (lane 0 writes x0^2+x1^2+x2^2 — removes
// the standalone d2_kernel launch at zero extra traffic).
// ---------------------------------------------------------------------------
__global__ __launch_bounds__(256) void dual3_kernel(
    const float* __restrict__ x, const float* __restrict__ w0a,
    const float* __restrict__ b1,
    float* __restrict__ hxi, float* __restrict__ hxj,
    float* __restrict__ d2out) {
  __shared__ float Cs[3 * HID], Bs[3 * HID], bs[HID];
  for (int t = threadIdx.x; t < 3 * HID; t += 256) {
    float bv = w0a[192 + t];
    Cs[t] = w0a[t] - bv;
    Bs[t] = bv;
  }
  if (threadIdx.x < HID) bs[threadIdx.x] = b1[threadIdx.x];
  __syncthreads();

  const int lane = threadIdx.x & 63;
  const int wv   = __builtin_amdgcn_readfirstlane(threadIdx.x >> 6);
  const int node0 = blockIdx.x * 32;
#pragma unroll 1
  for (int it = 0; it < 8; ++it) {
    const int n = node0 + it * 4 + wv;               // uniform
    const float* xr = x + (size_t)n * 3;             // uniform -> s_load
    float x0 = xr[0], x1 = xr[1], x2 = xr[2];
    float hi = bs[lane];
    hi = fmaf(x0, Cs[0 * HID + lane], hi);
    hi = fmaf(x1, Cs[1 * HID + lane], hi);
    hi = fmaf(x2, Cs[2 * HID + lane], hi);
    float hj = x0 * Bs[0 * HID + lane];
    hj = fmaf(x1, Bs[1 * HID + lane], hj);
    hj = fmaf(x2, Bs[2 * HID + lane], hj);
    hxi[(size_t)n * HID + lane] = hi;
    hxj[(size_t)n * HID + lane] = hj;
    if (lane == 0)
      d2out[n] = fmaf(x0, x0, fmaf(x1, x1, x2 * x2));
  }
}

// ---------------------------------------------------------------------------
// bn_reduce_finalize: 512 threads, 512 partial groups (4 grp x 128).
// (R9 lesson: per-block device-scope fences in the knn kernels cost ~90 us
// each dispatch in cross-XCD L2 writeback — this 1-block kernel is cheaper.)
// ---------------------------------------------------------------------------
__global__ __launch_bounds__(512) void bn_reduce_finalize_kernel(
    const float* __restrict__ g, const float* __restrict__ be,
    const float* __restrict__ partial, float* __restrict__ stats) {
  const int t   = threadIdx.x & 127;                 // 0..127
  const int grp = threadIdx.x >> 7;                  // 0..3
  float a0 = 0.f, a1 = 0.f, a2 = 0.f, a3 = 0.f;
  const int gb0 = grp * 128;
  for (int gb = gb0; gb < gb0 + 128; gb += 4) {
    a0 += partial[(size_t)(gb + 0) * 128 + t];
    a1 += partial[(size_t)(gb + 1) * 128 + t];
    a2 += partial[(size_t)(gb + 2) * 128 + t];
    a3 += partial[(size_t)(gb + 3) * 128 + t];
  }
  __shared__ float sm[4][128];
  sm[grp][t] = (a0 + a1) + (a2 + a3);
  __syncthreads();
  if (threadIdx.x < 128)
    sm[0][t] = (sm[0][t] + sm[1][t]) + (sm[2][t] + sm[3][t]);
  __syncthreads();
  if (threadIdx.x < HID) {
    const float inv_n = 1.f / (float)(BATCH * NPTS * K_NN);
    float m = sm[0][t] * inv_n;
    float v = sm[0][HID + t] * inv_n - m * m;
    float A = g[t] * rsqrtf(v + BN_EPS);
    stats[128 + t] = A;
    stats[192 + t] = be[t] - m * A;
  }
}

// ---------------------------------------------------------------------------
// egapply_gemm: BN-apply + relu + mean-over-K + W2 + b2 + fused d2 of the
// output row + fused bf16 3-way split + (last layer) atomic global-mean-pool
// accumulation (replaces pool_kernel; pooled zeroed via hipMemsetAsync).
// ---------------------------------------------------------------------------
__global__ __launch_bounds__(256) void egapply_gemm_kernel(
    const int* __restrict__ idx, const float* __restrict__ hxi,
    const float* __restrict__ hxj, const float* __restrict__ stats,
    const float* __restrict__ W2, const float* __restrict__ b2,
    float* __restrict__ out, float* __restrict__ d2out,
    unsigned short* __restrict__ xsh, unsigned short* __restrict__ xsm,
    unsigned short* __restrict__ xsl, float* __restrict__ pooled) {
  __shared__ float w2s[HID * HID];
  __shared__ float red[32][HID];
  for (int t = threadIdx.x; t < HID * HID; t += 256) w2s[t] = W2[t];

  const int lane = threadIdx.x & 63;
  const int wv   = __builtin_amdgcn_readfirstlane(threadIdx.x >> 6);
  const int node0 = blockIdx.x * 32;
  const float A = stats[128 + lane], Bc = stats[192 + lane];

#pragma unroll 1
  for (int it = 0; it < 4; ++it) {
    const int n0 = node0 + it * 8 + wv;              // uniform
    const int n1 = n0 + 4;
    const int bbase = (n0 >> 10) << 10;
    const int* ip0 = idx + (size_t)n0 * K_NN;        // uniform -> s_load
    const int* ip1 = idx + (size_t)n1 * K_NN;
    int j0[K_NN], j1[K_NN];
#pragma unroll
    for (int k = 0; k < K_NN; ++k) { j0[k] = ip0[k]; j1[k] = ip1[k]; }
    const float hv0 = hxi[(size_t)n0 * HID + lane];
    const float hv1 = hxi[(size_t)n1 * HID + lane];
    float v0[K_NN], v1[K_NN];
#pragma unroll
    for (int k = 0; k < K_NN; ++k) {
      v0[k] = hxj[(size_t)(bbase + j0[k]) * HID + lane];
      v1[k] = hxj[(size_t)(bbase + j1[k]) * HID + lane];
    }
    float a0 = 0.f, a1 = 0.f;
#pragma unroll
    for (int k = 0; k < K_NN; ++k) {
      a0 += fmaxf(fmaf(A, hv0 + v0[k], Bc), 0.f);
      a1 += fmaxf(fmaf(A, hv1 + v1[k], Bc), 0.f);
    }
    red[it * 8 + wv][lane] = a0;
    red[it * 8 + 4 + wv][lane] = a1;
  }
  __syncthreads();

  const float b2f = b2[lane];
  const float inv = 1.f / (float)K_NN;
  float psum = 0.f;
#pragma unroll 2
  for (int p = 0; p < 8; ++p) {
    int rr = p * 4 + wv;                             // uniform row
    float acc0 = 0.f, acc1 = 0.f;
#pragma unroll 8
    for (int h = 0; h < HID; h += 2) {
      acc0 = fmaf(red[rr][h],     w2s[h * HID + lane],       acc0);
      acc1 = fmaf(red[rr][h + 1], w2s[(h + 1) * HID + lane], acc1);
    }
    float val = fmaf(acc0 + acc1, inv, b2f);
    const size_t o = (size_t)(node0 + rr) * HID + lane;
    out[o] = val;
    psum += val;

    // bf16 3-way split (RNE, Sterbenz-exact residuals)
    unsigned u = __float_as_uint(val);
    unsigned short hh = (unsigned short)((u + 0x7FFFu + ((u >> 16) & 1u)) >> 16);
    float r1 = val - __uint_as_float((unsigned)hh << 16);
    unsigned ur = __float_as_uint(r1);
    unsigned short mm = (unsigned short)((ur + 0x7FFFu + ((ur >> 16) & 1u)) >> 16);
    float r2 = r1 - __uint_as_float((unsigned)mm << 16);
    unsigned ur2 = __float_as_uint(r2);
    unsigned short ll = (unsigned short)((ur2 + 0x7FFFu + ((ur2 >> 16) & 1u)) >> 16);
    xsh[o] = hh; xsm[o] = mm; xsl[o] = ll;

    float sq = val * val;                            // fused d2 of the row
#pragma unroll
    for (int off = 1; off < 64; off <<= 1) sq += __shfl_xor(sq, off, 64);
    if (lane == 0) d2out[node0 + rr] = sq;
  }

  if (pooled != nullptr) {                           // last layer: fused pool
    __syncthreads();                                 // red dead -> reuse
    red[wv][lane] = psum;
    __syncthreads();
    if (threadIdx.x < HID) {
      const int bb = node0 >> 10;
      float s = (red[0][lane] + red[1][lane]) + (red[2][lane] + red[3][lane]);
      atomicAdd(&pooled[bb * HID + lane], s * (1.f / (float)NPTS));
    }
  }
}

// ---------------------------------------------------------------------------
__global__ __launch_bounds__(256) void head_kernel(const float* __restrict__ pooled,
    const float* __restrict__ wf1, const float* __restrict__ bf1,
    const float* __restrict__ gf, const float* __restrict__ bef,
    const float* __restrict__ wf2, const float* __restrict__ bf2,
    float* __restrict__ out) {
  __shared__ float pl[BATCH * HID];
  __shared__ float t[BATCH * 32];
  __shared__ float Ab[32], Bb[32];
  for (int i = threadIdx.x; i < BATCH * HID; i += 256) pl[i] = pooled[i];
  __syncthreads();
  for (int i = threadIdx.x; i < BATCH * 32; i += 256) {
    int s = i >> 5, f1 = i & 31;
    float acc = bf1[f1];
    for (int h = 0; h < HID; ++h) acc = fmaf(pl[s * HID + h], wf1[h * 32 + f1], acc);
    t[i] = acc;
  }
  __syncthreads();
  if (threadIdx.x < 32) {
    int f1 = threadIdx.x;
    float m = 0.f;
    for (int s = 0; s < BATCH; ++s) m += t[s * 32 + f1];
    m *= (1.f / (float)BATCH);
    float v = 0.f;
    for (int s = 0; s < BATCH; ++s) { float d = t[s * 32 + f1] - m; v = fmaf(d, d, v); }
    v *= (1.f / (float)BATCH);
    float A = gf[f1] * rsqrtf(v + BN_EPS);
    Ab[f1] = A; Bb[f1] = bef[f1] - m * A;
  }
  __syncthreads();
  for (int i = threadIdx.x; i < BATCH * 32; i += 256) {
    int f1 = i & 31;
    t[i] = fmaxf(fmaf(Ab[f1], t[i], Bb[f1]), 0.f);
  }
  __syncthreads();
  if (threadIdx.x < BATCH * 2) {
    int s = threadIdx.x >> 1, o = threadIdx.x & 1;
    float acc = bf2[o];
    for (int f1 = 0; f1 < 32; ++f1) acc = fmaf(t[s * 32 + f1], wf2[f1 * 2 + o], acc);
    out[s * 2 + o] = acc;
  }
}

// ---------------------------------------------------------------------------
extern "C" void kernel_launch(void* const* d_in, const int* in_sizes, int n_in,
                              void* d_out, int out_size, void* d_ws, size_t ws_size,
                              hipStream_t stream) {
  const float* x   = (const float*)d_in[0];
  const float* w0a = (const float*)d_in[1];
  const float* b0a = (const float*)d_in[2];
  const float* g0  = (const float*)d_in[3];
  const float* be0 = (const float*)d_in[4];
  const float* w0b = (const float*)d_in[5];
  const float* b0b = (const float*)d_in[6];
  const float* wa  = (const float*)d_in[7];
  const float* ba  = (const float*)d_in[8];
  const float* ga  = (const float*)d_in[9];
  const float* bea = (const float*)d_in[10];
  const float* wb  = (const float*)d_in[11];
  const float* bb  = (const float*)d_in[12];
  const float* wf1 = (const float*)d_in[13];
  const float* bf1 = (const float*)d_in[14];
  const float* gf  = (const float*)d_in[15];
  const float* bef = (const float*)d_in[16];
  const float* wf2 = (const float*)d_in[17];
  const float* bf2 = (const float*)d_in[18];

  float* ws = (float*)d_ws;
  const size_t HN = (size_t)BATCH * NPTS * HID;         // 2,097,152
  const size_t ROWS = (size_t)BATCH * NPTS;             // 32768
  float* bufA    = ws;                                  // HN
  float* bufB    = bufA + HN;                           // HN
  float* hxi     = bufB + HN;                           // HN
  float* hxjb    = hxi + HN;                            // HN
  int*   idxb    = (int*)(hxjb + HN);                   // ROWS*12
  float* d2buf   = (float*)(idxb + ROWS * K_NN);        // ROWS
  float* stats   = d2buf + ROWS;                        // 256
  float* partial = stats + 256;                         // 512*128 used
  float* pooled  = partial + 1024 * 128;                // 2048
  unsigned short* xsh = (unsigned short*)(pooled + 2048);   // HN bf16
  unsigned short* xsm = xsh + HN;
  unsigned short* xsl = xsm + HN;
  // total ~46 MB of workspace

  hipMemsetAsync(pooled, 0, BATCH * HID * sizeof(float), stream);

  // ---- layer 0 (C=3, gather path) ----
  dual3_kernel<<<1024, 256, 0, stream>>>(x, w0a, b0a, hxi, hxjb, d2buf);
  knn3_kernel<<<dim3(16, BATCH), 512, 0, stream>>>(x, d2buf, idxb, hxi, hxjb, partial);
  bn_reduce_finalize_kernel<<<1, 512, 0, stream>>>(g0, be0, partial, stats);
  egapply_gemm_kernel<<<1024, 256, 0, stream>>>(idxb, hxi, hxjb, stats, w0b, b0b,
                                                bufA, d2buf, xsh, xsm, xsl, nullptr);

  // ---- layers 1..3 (rowgemm2 -> fused knn64+stats -> finalize -> egapply) ----
  const float* cur = bufA;
  float* nxt = bufB;
  for (int i = 0; i < 3; ++i) {
    rowgemm2_kernel<<<(int)(ROWS / 32), 256, 0, stream>>>(cur, wa + (size_t)i * 8192,
                                                          ba + i * HID, hxi, hxjb);
    knn64_mfma_kernel<<<dim3(16, BATCH), 512, 0, stream>>>(xsh, xsm, xsl, d2buf, idxb,
                                                           hxi, hxjb, partial);
    bn_reduce_finalize_kernel<<<1, 512, 0, stream>>>(ga + i * HID, bea + i * HID, partial, stats);
    egapply_gemm_kernel<<<1024, 256, 0, stream>>>(idxb, hxi, hxjb, stats,
                                                  wb + (size_t)i * 4096, bb + i * HID,
                                                  nxt, d2buf, xsh, xsm, xsl,
                                                  (i == 2) ? pooled : nullptr);
    const float* t = cur; cur = nxt; nxt = (float*)t;
  }

  head_kernel<<<1, 256, 0, stream>>>(pooled, wf1, bf1, gf, bef, wf2, bf2, (float*)d_out);
}